// Round 17
// baseline (185.031 us; speedup 1.0000x reference)
//
#include <hip/hip_runtime.h>

typedef __bf16 bf16_t;
typedef __bf16 bf16x8 __attribute__((ext_vector_type(8)));
typedef float  floatx4 __attribute__((ext_vector_type(4)));
typedef int    intx8  __attribute__((ext_vector_type(8)));

#define B_  2
#define C_  512
#define N_  4096   // 64*64 pixels
#define EPS 1e-5f
#define SCALE 0.044194173824159216f  // 512^-0.5
#define SA_W 122   // E8M0 2^-5: compensates x32 weight pre-scale
#define SA_1 127   // E8M0 1.0

// ---------------------------------------------------------------------------
// async global->LDS, 16B per lane (wave-uniform base + lane*16 at all sites).
// ---------------------------------------------------------------------------
__device__ __forceinline__ void gl2lds16(const void* g, void* l) {
  __builtin_amdgcn_global_load_lds(
      (const __attribute__((address_space(1))) void*)g,
      (__attribute__((address_space(3))) void*)l, 16, 0, 0);
}

// fp8 e4m3 (OCP) convert helpers via v_cvt_pk_fp8_f32.
__device__ __forceinline__ unsigned char f8(float x) {
  return (unsigned char)(__builtin_amdgcn_cvt_pk_fp8_f32(x, x, 0, false) & 0xff);
}
__device__ __forceinline__ unsigned int pk4(float a, float b, float c, float d) {
  unsigned int p = __builtin_amdgcn_cvt_pk_fp8_f32(a, b, 0, false);
  return __builtin_amdgcn_cvt_pk_fp8_f32(c, d, p, true);
}

// MX-scaled fp8 MFMA, K=128. SA/SB are E8M0 scale bytes (127 = 1.0).
template <int SA, int SB>
__device__ __forceinline__ floatx4 mfma128_fp8(intx8 a, intx8 b, floatx4 c) {
  return __builtin_amdgcn_mfma_scale_f32_16x16x128_f8f6f4(
      a, b, c, 0, 0, 0, SA, 0, SB);
}

union Frag32 { uint4 q[2]; intx8 v; };

// ---------------------------------------------------------------------------
// Fused QKV (MX fp8, BK=128): A = wqkv8[1536][512] (x32-scaled fp8,
// scale_a=2^-5), B = h8[8192][512] fp8. 128x128 tile, 256 thr, 4 K-iters.
// q/k: fp8 packed 4B transposed stores; v: fp8 [c][n] via LDS-transpose.
// ---------------------------------------------------------------------------
__global__ __launch_bounds__(256) void gemm_qkv(
    const unsigned char* __restrict__ Wqkv8, const unsigned char* __restrict__ h8,
    unsigned char* __restrict__ q8, unsigned char* __restrict__ k8,
    unsigned char* __restrict__ v8,
    const float* __restrict__ bq, const float* __restrict__ bk,
    const float* __restrict__ bv) {
  __shared__ __align__(16) unsigned char smem[32768];
  unsigned char* As = smem;            // 128 x 128B = 16 KB
  unsigned char* Bs = smem + 16384;    // 128 x 128B = 16 KB
  const int m0 = blockIdx.y * 128, n0 = blockIdx.x * 128;

  const int tid = threadIdx.x;
  const int w = tid >> 6, l = tid & 63;
  const int wm = (w >> 1) * 64, wn = (w & 1) * 64;
  const int lrow = l & 15, lq = l >> 4;
  const int key = lrow & 7;
  const int e0 = (2 * lq) ^ key;

  floatx4 acc[4][4];
  floatx4 zero = {0.f, 0.f, 0.f, 0.f};
#pragma unroll
  for (int mm = 0; mm < 4; mm++)
#pragma unroll
    for (int nn = 0; nn < 4; nn++) acc[mm][nn] = zero;

  for (int k0 = 0; k0 < C_; k0 += 128) {
#pragma unroll
    for (int p = 0; p < 4; p++) {              // A: 1024 chunks of 16B
      int gch = p * 256 + tid;
      int r = gch >> 3;
      int cg = (gch & 7) ^ (r & 7);
      gl2lds16(Wqkv8 + (size_t)(m0 + r) * C_ + k0 + cg * 16, As + gch * 16);
    }
#pragma unroll
    for (int p = 0; p < 4; p++) {              // B: 1024 chunks of 16B
      int gch = p * 256 + tid;
      int r = gch >> 3;
      int cg = (gch & 7) ^ (r & 7);
      gl2lds16(h8 + (size_t)(n0 + r) * C_ + k0 + cg * 16, Bs + gch * 16);
    }
    __syncthreads();

    intx8 af[4], bfr[4];
#pragma unroll
    for (int mm = 0; mm < 4; mm++) {
      int row = wm + mm * 16 + lrow;
      Frag32 f;
      f.q[0] = *(const uint4*)(As + row * 128 + e0 * 16);
      f.q[1] = *(const uint4*)(As + row * 128 + (e0 ^ 1) * 16);
      af[mm] = f.v;
    }
#pragma unroll
    for (int nn = 0; nn < 4; nn++) {
      int row = wn + nn * 16 + lrow;
      Frag32 f;
      f.q[0] = *(const uint4*)(Bs + row * 128 + e0 * 16);
      f.q[1] = *(const uint4*)(Bs + row * 128 + (e0 ^ 1) * 16);
      bfr[nn] = f.v;
    }
#pragma unroll
    for (int mm = 0; mm < 4; mm++)
#pragma unroll
      for (int nn = 0; nn < 4; nn++)
        acc[mm][nn] = mfma128_fp8<SA_W, SA_1>(af[mm], bfr[nn], acc[mm][nn]);
    __syncthreads();
  }

  const int q4 = lq * 4;
  const int mat = m0 >> 9;  // 0=q 1=k 2=v
  const float* bias = (mat == 0) ? bq : (mat == 1) ? bk : bv;

  if (mat < 2) {
    unsigned char* ot = (mat == 0) ? q8 : k8;
#pragma unroll
    for (int mm = 0; mm < 4; mm++) {
#pragma unroll
      for (int nn = 0; nn < 4; nn++) {
        int n = n0 + wn + nn * 16 + lrow;       // pixel 0..8191
        int mloc = m0 - mat * 512 + wm + mm * 16 + q4;
        floatx4 a = acc[mm][nn];
        unsigned int p = pk4(a[0] + bias[mloc + 0], a[1] + bias[mloc + 1],
                             a[2] + bias[mloc + 2], a[3] + bias[mloc + 3]);
        *(unsigned int*)(ot + (size_t)n * 512 + mloc) = p;
      }
    }
  } else {
    // v: fp8 tile 128 ch-rows x 128 pixel-cols = 128B/row (8 x 16B chunks)
    unsigned char* tile8 = smem;
#pragma unroll
    for (int mm = 0; mm < 4; mm++) {
#pragma unroll
      for (int nn = 0; nn < 4; nn++) {
        int colp = wn + nn * 16 + lrow;         // pixel-local 0..127
        floatx4 a = acc[mm][nn];
#pragma unroll
        for (int r = 0; r < 4; r++) {
          int row = wm + mm * 16 + q4 + r;      // channel-local 0..127
          int ch = (colp >> 4) ^ ((row >> 2) & 7);
          tile8[row * 128 + ch * 16 + (colp & 15)] =
              f8(a[r] + bias[m0 - 1024 + row]);
        }
      }
    }
    __syncthreads();
    const int bb = n0 >> 12, nl0 = n0 & 4095;
    const int mloc0 = m0 - 1024;
#pragma unroll
    for (int i = 0; i < 4; i++) {
      int c = i * 256 + tid;                    // 1024 chunks of 16B
      int row = c >> 3, k = c & 7;
      int ch = k ^ ((row >> 2) & 7);
      uint4 d = *(const uint4*)(tile8 + row * 128 + ch * 16);
      *(uint4*)(v8 + (size_t)bb * (C_ * N_) + (size_t)(mloc0 + row) * N_ +
                nl0 + k * 16) = d;
    }
  }
}

// ---------------------------------------------------------------------------
// Scores+exp (MX fp8 K=128, scale=1.0): S8[i][j] = fp8(exp(q.k * SCALE)).
// TRANSPOSED compute (A=k8 m-dim=j, B=q8 n-dim=i). BK=128, 128B rows,
// 8-chunk XOR swizzle, b128-pair fragments (conflict-free, r14/r15).
// No max-subtraction (|s|<~2). L row-sums fp32 via shfl + vector atomics.
// XCD-swizzled 1D grid.
// ---------------------------------------------------------------------------
__global__ __launch_bounds__(256) void gemm_scores(
    const unsigned char* __restrict__ q8, const unsigned char* __restrict__ k8,
    unsigned char* __restrict__ S8, size_t sstride, float* __restrict__ L,
    int zbase, int nz) {
  __shared__ __align__(16) unsigned char As[128 * 128];   // keys j
  __shared__ __align__(16) unsigned char Bs[128 * 128];   // queries i
  const int id = blockIdx.x;
  const int x = id & 7, s = id >> 3;
  const int mi = s & 3, n = (s >> 2) & 31;
  const int zloc = (nz == 2) ? (s >> 7) : 0;
  const int z = (nz == 2) ? zloc : zbase;
  const int m = x * 4 + mi;
  const int m0 = m * 128, n0 = n * 128;

  const unsigned char* A = k8 + (size_t)z * (N_ * C_);
  const unsigned char* B = q8 + (size_t)z * (N_ * C_);
  unsigned char* Sb = S8 + (size_t)zloc * sstride;
  float* Lb = L + (size_t)zloc * N_;

  const int tid = threadIdx.x;
  const int w = tid >> 6, l = tid & 63;
  const int wm = (w >> 1) * 64, wn = (w & 1) * 64;
  const int lrow = l & 15, lq = l >> 4;
  const int key = lrow & 7;
  const int e0 = (2 * lq) ^ key;

  floatx4 acc[4][4];
  floatx4 zero = {0.f, 0.f, 0.f, 0.f};
#pragma unroll
  for (int mm = 0; mm < 4; mm++)
#pragma unroll
    for (int nn = 0; nn < 4; nn++) acc[mm][nn] = zero;

  for (int k0 = 0; k0 < C_; k0 += 128) {
#pragma unroll
    for (int p = 0; p < 4; p++) {
      int gch = p * 256 + tid;
      int r = gch >> 3;
      int cg = (gch & 7) ^ (r & 7);
      gl2lds16(A + (size_t)(m0 + r) * C_ + k0 + cg * 16, As + gch * 16);
    }
#pragma unroll
    for (int p = 0; p < 4; p++) {
      int gch = p * 256 + tid;
      int r = gch >> 3;
      int cg = (gch & 7) ^ (r & 7);
      gl2lds16(B + (size_t)(n0 + r) * C_ + k0 + cg * 16, Bs + gch * 16);
    }
    __syncthreads();

    intx8 af[4], bfr[4];
#pragma unroll
    for (int mm = 0; mm < 4; mm++) {
      int row = wm + mm * 16 + lrow;
      Frag32 f;
      f.q[0] = *(const uint4*)(As + row * 128 + e0 * 16);
      f.q[1] = *(const uint4*)(As + row * 128 + (e0 ^ 1) * 16);
      af[mm] = f.v;
    }
#pragma unroll
    for (int nn = 0; nn < 4; nn++) {
      int row = wn + nn * 16 + lrow;
      Frag32 f;
      f.q[0] = *(const uint4*)(Bs + row * 128 + e0 * 16);
      f.q[1] = *(const uint4*)(Bs + row * 128 + (e0 ^ 1) * 16);
      bfr[nn] = f.v;
    }
#pragma unroll
    for (int mm = 0; mm < 4; mm++)
#pragma unroll
      for (int nn = 0; nn < 4; nn++)
        acc[mm][nn] = mfma128_fp8<SA_1, SA_1>(af[mm], bfr[nn], acc[mm][nn]);
    __syncthreads();
  }

  float lsum[4] = {0.f, 0.f, 0.f, 0.f};
#pragma unroll
  for (int mm = 0; mm < 4; mm++) {
#pragma unroll
    for (int nn = 0; nn < 4; nn++) {
      int i  = n0 + wn + nn * 16 + lrow;   // query index
      int jb = m0 + wm + mm * 16 + lq * 4; // key index (4 consecutive)
      floatx4 a = acc[mm][nn];
      float e0v = __expf(a[0] * SCALE);
      float e1v = __expf(a[1] * SCALE);
      float e2v = __expf(a[2] * SCALE);
      float e3v = __expf(a[3] * SCALE);
      lsum[nn] += (e0v + e1v) + (e2v + e3v);
      *(unsigned int*)(Sb + (size_t)i * N_ + jb) = pk4(e0v, e1v, e2v, e3v);
    }
  }
#pragma unroll
  for (int nn = 0; nn < 4; nn++) {
    float vsum = lsum[nn];
    vsum += __shfl_xor(vsum, 16);
    vsum += __shfl_xor(vsum, 32);
    if (lq == 0)
      atomicAdd(Lb + n0 + wn + nn * 16 + lrow, vsum);
  }
}

// ---------------------------------------------------------------------------
// PV (MX fp8 K=128): O8[z,i,c] = fp8((1/L_i) sum_j P8 v8). RETILED 128x128
// (r16 was 128x64): S row-panel re-read x4 instead of x8, staging 1.0B per
// output (was 1.5), 16 mfma/barrier (was 8). 512 threads, split-K halves
// (per-wave 64x64, acc[4][4]); 64KB staging. Combine: wk1 dumps acc to a
// 64KB fp32 buf (overlays staging post-barrier); wk0 reads ALL slots into
// acc, barrier, THEN overwrites smem with the 128x128 bf16 transpose tile
// (read-before-overwrite ordering); packed fp8 8B stores.
// ---------------------------------------------------------------------------
__global__ __launch_bounds__(512) void gemm_pv(
    const unsigned char* __restrict__ S8, size_t sstride,
    const unsigned char* __restrict__ v8, const float* __restrict__ L,
    unsigned char* __restrict__ O8, int zbase, int nz) {
  __shared__ __align__(16) char smem[65536];
  const int id = blockIdx.x;
  int nb, mb, zloc;
  if (nz == 2) { nb = id >> 6; int g = id & 63; mb = g >> 1; zloc = g & 1; }
  else         { nb = id >> 5; mb = id & 31; zloc = 0; }
  const int z = (nz == 2) ? zloc : zbase;

  const unsigned char* A = S8 + (size_t)zloc * sstride;  // [4096][4096] fp8
  const unsigned char* B = v8 + (size_t)z * (C_ * N_);   // [512][4096] fp8
  const float* Lb = L + (size_t)zloc * N_;
  const int m0 = mb * 128, n0 = nb * 128;

  const int tid = threadIdx.x;
  const int w = tid >> 6, l = tid & 63;
  const int wk = w >> 2;                 // K-half
  const int wl = w & 3;                  // wave within half (2x2)
  const int t2 = tid & 255;
  unsigned char* Ah = (unsigned char*)smem + wk * 16384;           // 16KB each
  unsigned char* Bh = (unsigned char*)(smem + 32768) + wk * 16384; // 16KB each

  const int wm = (wl >> 1) * 64, wn = (wl & 1) * 64;
  const int lrow = l & 15, lq = l >> 4;
  const int key = lrow & 7;
  const int e0 = (2 * lq) ^ key;

  floatx4 acc[4][4];
  floatx4 zero = {0.f, 0.f, 0.f, 0.f};
#pragma unroll
  for (int mm = 0; mm < 4; mm++)
#pragma unroll
    for (int nn = 0; nn < 4; nn++) acc[mm][nn] = zero;

  const int kbase = wk * 2048;
  for (int kk = 0; kk < 2048; kk += 128) {
    const int k0 = kbase + kk;
#pragma unroll
    for (int p = 0; p < 4; p++) {            // A: 1024 chunks of 16B
      int gch = p * 256 + t2;
      int r = gch >> 3;
      int cg = (gch & 7) ^ (r & 7);
      gl2lds16(A + (size_t)(m0 + r) * 4096 + k0 + cg * 16, Ah + gch * 16);
    }
#pragma unroll
    for (int p = 0; p < 4; p++) {            // B: 1024 chunks of 16B
      int gch = p * 256 + t2;
      int r = gch >> 3;
      int cg = (gch & 7) ^ (r & 7);
      gl2lds16(B + (size_t)(n0 + r) * 4096 + k0 + cg * 16, Bh + gch * 16);
    }
    __syncthreads();

    intx8 af[4], bfr[4];
#pragma unroll
    for (int mm = 0; mm < 4; mm++) {
      int row = wm + mm * 16 + lrow;
      Frag32 f;
      f.q[0] = *(const uint4*)(Ah + row * 128 + e0 * 16);
      f.q[1] = *(const uint4*)(Ah + row * 128 + (e0 ^ 1) * 16);
      af[mm] = f.v;
    }
#pragma unroll
    for (int nn = 0; nn < 4; nn++) {
      int row = wn + nn * 16 + lrow;
      Frag32 f;
      f.q[0] = *(const uint4*)(Bh + row * 128 + e0 * 16);
      f.q[1] = *(const uint4*)(Bh + row * 128 + (e0 ^ 1) * 16);
      bfr[nn] = f.v;
    }
#pragma unroll
    for (int mm = 0; mm < 4; mm++)
#pragma unroll
      for (int nn = 0; nn < 4; nn++)
        acc[mm][nn] = mfma128_fp8<SA_1, SA_1>(af[mm], bfr[nn], acc[mm][nn]);
    __syncthreads();
  }

  // combine halves: wk1 dumps 16 tiles into 64KB fp32 buf (= all of smem)
  floatx4* buf = (floatx4*)smem;          // 4096 slots = 64KB
  const int lanebase = wl * 64 + l;
  if (wk == 1) {
#pragma unroll
    for (int mm = 0; mm < 4; mm++)
#pragma unroll
      for (int nn = 0; nn < 4; nn++)
        buf[(mm * 4 + nn) * 256 + lanebase] = acc[mm][nn];
  }
  __syncthreads();

  const int q4 = lq * 4;
  if (wk == 0) {
    // read ALL buf slots + normalize into acc (before smem is overwritten)
#pragma unroll
    for (int mm = 0; mm < 4; mm++) {
      const int rowb = wm + mm * 16 + q4;
      float rv0 = 1.0f / Lb[m0 + rowb + 0];
      float rv1 = 1.0f / Lb[m0 + rowb + 1];
      float rv2 = 1.0f / Lb[m0 + rowb + 2];
      float rv3 = 1.0f / Lb[m0 + rowb + 3];
#pragma unroll
      for (int nn = 0; nn < 4; nn++) {
        floatx4 a = acc[mm][nn] + buf[(mm * 4 + nn) * 256 + lanebase];
        a[0] *= rv0; a[1] *= rv1; a[2] *= rv2; a[3] *= rv3;
        acc[mm][nn] = a;
      }
    }
  }
  __syncthreads();   // all buf reads complete before tile overwrite

  // transpose tile: 128 pixel-rows x 128 ch bf16 (16 chunks/row) = 32KB
  bf16_t* tile = (bf16_t*)smem;
  if (wk == 0) {
#pragma unroll
    for (int mm = 0; mm < 4; mm++) {
      const int rowb = wm + mm * 16 + q4;
#pragma unroll
      for (int nn = 0; nn < 4; nn++) {
        floatx4 a = acc[mm][nn];
        int colp = wn + nn * 16 + lrow;       // channel-local 0..127
#pragma unroll
        for (int r = 0; r < 4; r++) {
          int row = rowb + r;                 // pixel-local 0..127
          int ch = (colp >> 3) ^ ((row >> 2) & 15);
          tile[row * 128 + ch * 8 + (colp & 7)] = (bf16_t)a[r];
        }
      }
    }
  }
  __syncthreads();
#pragma unroll
  for (int i = 0; i < 4; i++) {
    int c = i * 512 + tid;                    // 2048 chunks, 512 threads
    int row = c >> 4, k = c & 15;
    int ch = k ^ ((row >> 2) & 15);
    bf16x8 d = *(const bf16x8*)(tile + row * 128 + ch * 8);
    uint2 p;
    p.x = pk4((float)d[0], (float)d[1], (float)d[2], (float)d[3]);
    p.y = pk4((float)d[4], (float)d[5], (float)d[6], (float)d[7]);
    *(uint2*)(O8 + ((size_t)z * N_ + m0 + row) * C_ + n0 + k * 8) = p;
  }
}

// ---------------------------------------------------------------------------
// Final (MX fp8, BK=128): out[b,c,n] = x + wo.O + bo. A = wo8[512][512]
// (x32-scaled fp8, scale_a=2^-5), B = O8[8192][512] fp8. BM=64 x BN=128;
// fp32 LDS-transpose epilogue with float4 residual loads + stores.
// ---------------------------------------------------------------------------
__global__ __launch_bounds__(256) void gemm_final(
    const unsigned char* __restrict__ wo8, const unsigned char* __restrict__ O8,
    const float* __restrict__ bo, const float* __restrict__ x,
    float* __restrict__ out) {
  __shared__ __align__(16) unsigned char smem[32768];
  unsigned char* As = smem;            // 64 x 128B = 8 KB
  unsigned char* Bs = smem + 8192;     // 128 x 128B = 16 KB
  const int m0 = blockIdx.y * 64, n0 = blockIdx.x * 128;

  const int tid = threadIdx.x;
  const int w = tid >> 6, l = tid & 63;
  const int wm = (w >> 1) * 32, wn = (w & 1) * 64;
  const int lrow = l & 15, lq = l >> 4;
  const int key = lrow & 7;
  const int e0 = (2 * lq) ^ key;

  floatx4 acc[2][4];
  floatx4 zero = {0.f, 0.f, 0.f, 0.f};
#pragma unroll
  for (int mm = 0; mm < 2; mm++)
#pragma unroll
    for (int nn = 0; nn < 4; nn++) acc[mm][nn] = zero;

  for (int k0 = 0; k0 < C_; k0 += 128) {
#pragma unroll
    for (int p = 0; p < 2; p++) {              // A: 512 chunks of 16B
      int gch = p * 256 + tid;
      int r = gch >> 3;
      int cg = (gch & 7) ^ (r & 7);
      gl2lds16(wo8 + (size_t)(m0 + r) * C_ + k0 + cg * 16, As + gch * 16);
    }
#pragma unroll
    for (int p = 0; p < 4; p++) {              // B: 1024 chunks of 16B
      int gch = p * 256 + tid;
      int r = gch >> 3;
      int cg = (gch & 7) ^ (r & 7);
      gl2lds16(O8 + (size_t)(n0 + r) * C_ + k0 + cg * 16, Bs + gch * 16);
    }
    __syncthreads();

    intx8 af[2], bfr[4];
#pragma unroll
    for (int mm = 0; mm < 2; mm++) {
      int row = wm + mm * 16 + lrow;
      Frag32 f;
      f.q[0] = *(const uint4*)(As + row * 128 + e0 * 16);
      f.q[1] = *(const uint4*)(As + row * 128 + (e0 ^ 1) * 16);
      af[mm] = f.v;
    }
#pragma unroll
    for (int nn = 0; nn < 4; nn++) {
      int row = wn + nn * 16 + lrow;
      Frag32 f;
      f.q[0] = *(const uint4*)(Bs + row * 128 + e0 * 16);
      f.q[1] = *(const uint4*)(Bs + row * 128 + (e0 ^ 1) * 16);
      bfr[nn] = f.v;
    }
#pragma unroll
    for (int mm = 0; mm < 2; mm++)
#pragma unroll
      for (int nn = 0; nn < 4; nn++)
        acc[mm][nn] = mfma128_fp8<SA_W, SA_1>(af[mm], bfr[nn], acc[mm][nn]);
    __syncthreads();
  }

  const int q4 = lq * 4;
  // tile: 64 rows x 128 fp32 cols (32 chunks/row of 16B) = 32KB
  float* tile = (float*)smem;
#pragma unroll
  for (int mm = 0; mm < 2; mm++) {
#pragma unroll
    for (int nn = 0; nn < 4; nn++) {
      int colp = wn + nn * 16 + lrow;         // 0..127
      floatx4 a = acc[mm][nn];
#pragma unroll
      for (int r = 0; r < 4; r++) {
        int row = wm + mm * 16 + q4 + r;      // 0..63
        int ch = (colp >> 2) ^ ((row >> 2) & 31);
        tile[row * 128 + ch * 4 + (colp & 3)] = a[r] + bo[m0 + row];
      }
    }
  }
  __syncthreads();
  const int bb = n0 >> 12, nl0 = n0 & 4095;
#pragma unroll
  for (int i = 0; i < 8; i++) {
    int c = i * 256 + tid;                    // 2048 chunks
    int row = c >> 5, k = c & 31;
    int ch = k ^ ((row >> 2) & 31);
    float4 dv = *(const float4*)(tile + row * 128 + ch * 4);
    size_t off = ((size_t)(bb * C_ + m0 + row)) * N_ + nl0 + k * 4;
    float4 xv = *(const float4*)(x + off);
    dv.x += xv.x; dv.y += xv.y; dv.z += xv.z; dv.w += xv.w;
    *(float4*)(out + off) = dv;
  }
}

// ---------------------------------------------------------------------------
// Merged prep: blocks 0..4095 = weight fp32 -> fp8 convert, x32-scaled
// (qkv stacked + wo); blocks 4096..4607 = GN partial sums; 4608 = zero L.
// ---------------------------------------------------------------------------
__global__ __launch_bounds__(256) void prep_kernel(
    const float* __restrict__ s0, const float* __restrict__ s1,
    const float* __restrict__ s2, const float* __restrict__ s3,
    unsigned char* __restrict__ d_qkv8, unsigned char* __restrict__ d_o8,
    const float* __restrict__ x, float2* __restrict__ part,
    float* __restrict__ L) {
  const int id = blockIdx.x;
  const int tid = threadIdx.x;
  __shared__ float rs[4], rss[4];
  if (id < 4096) {
    int i = id * 256 + tid;
    int mat = i >> 18, idx = i & 262143;
    const float* s = (mat == 0) ? s0 : (mat == 1) ? s1 : (mat == 2) ? s2 : s3;
    if (mat < 3)
      d_qkv8[mat * 262144 + idx] = f8(s[idx] * 32.f);
    else
      d_o8[idx] = f8(s[idx] * 32.f);
  } else if (id < 4608) {
    const int sid = id - 4096;   // 0..511
    const float4* xp = (const float4*)(x + (size_t)sid * 8192);
    float s = 0.f, ss = 0.f;
#pragma unroll
    for (int i = 0; i < 8; i++) {
      float4 v = xp[tid + i * 256];
      s += v.x + v.y + v.z + v.w;
      ss += v.x * v.x + v.y * v.y + v.z * v.z + v.w * v.w;
    }
#pragma unroll
    for (int off = 32; off; off >>= 1) {
      s += __shfl_down(s, off);
      ss += __shfl_down(ss, off);
    }
    if ((tid & 63) == 0) { rs[tid >> 6] = s; rss[tid >> 6] = ss; }
    __syncthreads();
    if (tid == 0) {
      float2 p;
      p.x = rs[0] + rs[1] + rs[2] + rs[3];
      p.y = rss[0] + rss[1] + rss[2] + rss[3];
      part[sid] = p;
    }
  } else {
    // zero L: 2*4096 floats = 2048 float4
    float4 z4 = {0.f, 0.f, 0.f, 0.f};
    float4* Lp = (float4*)L;
#pragma unroll
    for (int i = 0; i < 8; i++) Lp[tid + i * 256] = z4;
  }
}

// ---------------------------------------------------------------------------
// zero L for one batch (nz==1 path): 4096 floats = 1024 float4.
// ---------------------------------------------------------------------------
__global__ __launch_bounds__(256) void zeroL_kernel(float* __restrict__ L) {
  float4 z4 = {0.f, 0.f, 0.f, 0.f};
  ((float4*)L)[blockIdx.x * 256 + threadIdx.x] = z4;
}

// ---------------------------------------------------------------------------
// GroupNorm pass 2: normalize + transpose-write h8[b][n][c] fp8 (one 16B
// store per thread covering the group's 16 channels).
// ---------------------------------------------------------------------------
__global__ __launch_bounds__(256) void gn_apply(
    const float* __restrict__ x, const float* __restrict__ gamma,
    const float* __restrict__ beta, const float2* __restrict__ part,
    unsigned char* __restrict__ h8) {
  const int id = blockIdx.x;          // 1024
  const int nc = id & 15, g = (id >> 4) & 31, b = id >> 9;
  const int bg = b * 32 + g;
  float s = 0.f, ss = 0.f;
#pragma unroll
  for (int i = 0; i < 8; i++) {
    float2 p = part[bg * 8 + i];
    s += p.x; ss += p.y;
  }
  const float mean = s * (1.f / 65536.f);
  const float inv = rsqrtf(ss * (1.f / 65536.f) - mean * mean + EPS);

  __shared__ float tile[256 * 17];
  const int tid = threadIdx.x;
  const int n0 = nc * 256;
#pragma unroll
  for (int i = 0; i < 4; i++) {
    int lin = i * 256 + tid;
    int cl = lin >> 6;
    int n4 = (lin & 63) * 4;
    int c = g * 16 + cl;
    float ga = gamma[c], be = beta[c];
    float4 v = *(const float4*)(x + ((size_t)(b * C_ + c)) * N_ + n0 + n4);
    tile[(n4 + 0) * 17 + cl] = (v.x - mean) * inv * ga + be;
    tile[(n4 + 1) * 17 + cl] = (v.y - mean) * inv * ga + be;
    tile[(n4 + 2) * 17 + cl] = (v.z - mean) * inv * ga + be;
    tile[(n4 + 3) * 17 + cl] = (v.w - mean) * inv * ga + be;
  }
  __syncthreads();
  uint4 p;
  p.x = pk4(tile[tid * 17 + 0], tile[tid * 17 + 1],
            tile[tid * 17 + 2], tile[tid * 17 + 3]);
  p.y = pk4(tile[tid * 17 + 4], tile[tid * 17 + 5],
            tile[tid * 17 + 6], tile[tid * 17 + 7]);
  p.z = pk4(tile[tid * 17 + 8], tile[tid * 17 + 9],
            tile[tid * 17 + 10], tile[tid * 17 + 11]);
  p.w = pk4(tile[tid * 17 + 12], tile[tid * 17 + 13],
            tile[tid * 17 + 14], tile[tid * 17 + 15]);
  *(uint4*)(h8 + ((size_t)(b * N_ + n0 + tid)) * C_ + g * 16) = p;
}

// ---------------------------------------------------------------------------
extern "C" void kernel_launch(void* const* d_in, const int* in_sizes, int n_in,
                              void* d_out, int out_size, void* d_ws, size_t ws_size,
                              hipStream_t stream) {
  const float* x    = (const float*)d_in[0];
  const float* gn_w = (const float*)d_in[1];
  const float* gn_b = (const float*)d_in[2];
  const float* wq   = (const float*)d_in[3];
  const float* bq   = (const float*)d_in[4];
  const float* wk   = (const float*)d_in[5];
  const float* bk   = (const float*)d_in[6];
  const float* wv   = (const float*)d_in[7];
  const float* bv   = (const float*)d_in[8];
  const float* wo   = (const float*)d_in[9];
  const float* bo   = (const float*)d_in[10];
  float* out = (float*)d_out;

  char* ws = (char*)d_ws;
  unsigned char* h8    = (unsigned char*)(ws);              // [8192][512] 4MB
  unsigned char* q8    = (unsigned char*)(ws + (4u << 20)); // [8192][512] 4MB
  unsigned char* k8    = (unsigned char*)(ws + (8u << 20)); // [8192][512] 4MB
  unsigned char* v8    = (unsigned char*)(ws + (12u << 20));// [2][512][4096] 4MB
  unsigned char* O8    = (unsigned char*)(ws + (16u << 20));// [2][4096][512] 4MB
  unsigned char* wqkv8 = (unsigned char*)(ws + (20u << 20));// [1536][512] .75MB
  unsigned char* wo8   = (unsigned char*)(ws + (21u << 20));// [512][512] .25MB
  float2* gnp = (float2*)(ws + (22u << 20));                // [512] partials
  float*  L   = (float*)(ws + (22u << 20) + 8192);          // [2][4096] rowsums
  unsigned char* S8 = (unsigned char*)(ws + (24u << 20));   // 1-2 x 16 MB expS

  const size_t SN = (size_t)N_ * N_;                 // bytes per batch (fp8)
  const int nz = (ws_size >= (24u << 20) + 2 * SN) ? 2 : 1;

  prep_kernel<<<4609, 256, 0, stream>>>(wq, wk, wv, wo, wqkv8, wo8, x, gnp, L);
  gn_apply<<<1024, 256, 0, stream>>>(x, gn_w, gn_b, gnp, h8);

  // QKV both batches: M=1536, N=8192, K=512
  gemm_qkv<<<dim3(64, 12), 256, 0, stream>>>(wqkv8, h8, q8, k8, v8,
                                             bq, bk, bv);

  if (nz == 2) {
    gemm_scores<<<2048, 256, 0, stream>>>(q8, k8, S8, SN, L, 0, 2);
    gemm_pv<<<256, 512, 0, stream>>>(S8, SN, v8, L, O8, 0, 2);
  } else {
    for (int b = 0; b < B_; b++) {
      zeroL_kernel<<<4, 256, 0, stream>>>(L);
      gemm_scores<<<1024, 256, 0, stream>>>(q8, k8, S8, 0, L, b, 1);
      gemm_pv<<<128, 512, 0, stream>>>(S8, 0, v8, L, O8, b, 1);
    }
  }

  // Final: out = x + wo.O + bo.  M=512, N=8192, K=512
  gemm_final<<<dim3(64, 8), 256, 0, stream>>>(wo8, O8, bo, x, out);
}